// Round 1
// baseline (150.646 us; speedup 1.0000x reference)
//
#include <hip/hip_runtime.h>

#define HRR 256
#define LSZ 64
#define KK  15

// ---------------------------------------------------------------------------
// Kernel 1: per-point MLP (2 -> 200 -> 50), spek head -> pre_pan,
//           spak head (at h%4==1 && w%4==1) -> INV entries into workspace.
// One thread per point p in [0, B*HR*HR). Weight reads are wave-uniform
// (loop-counter indices off kernel-arg pointers) -> scalar loads / K$.
// ---------------------------------------------------------------------------
__global__ __launch_bounds__(256) void mlp_kernel(
    const float* __restrict__ coords, const float* __restrict__ hrhs,
    const float* __restrict__ w1,     const float* __restrict__ b1,
    const float* __restrict__ w2,     const float* __restrict__ b2,
    const float* __restrict__ w_spek, const float* __restrict__ b_spek,
    const float* __restrict__ w_spak, const float* __restrict__ b_spak,
    float* __restrict__ out_pan,      // B*HR*HR floats
    float* __restrict__ inv_ws)       // B*64*64*3 floats
{
    const int p   = blockIdx.x * blockDim.x + threadIdx.x;   // 0..524287
    const int b   = p >> 16;
    const int idx = p & 65535;
    const int h   = idx >> 8;
    const int w   = idx & 255;

    const float c0 = coords[p * 2 + 0];
    const float c1 = coords[p * 2 + 1];

    float acc[50];
#pragma unroll
    for (int j = 0; j < 50; ++j) acc[j] = b2[j];

    for (int k = 0; k < 200; ++k) {
        float h1 = fmaf(c0, w1[k], fmaf(c1, w1[200 + k], b1[k]));
        h1 = fmaxf(h1, 0.0f);
#pragma unroll
        for (int j = 0; j < 50; ++j)
            acc[j] = fmaf(h1, w2[k * 50 + j], acc[j]);
    }
#pragma unroll
    for (int j = 0; j < 50; ++j) acc[j] = fmaxf(acc[j], 0.0f);

    // spek head (5) -> pre_pan
    float s[5];
#pragma unroll
    for (int t = 0; t < 5; ++t) {
        float v = b_spek[t];
#pragma unroll
        for (int j = 0; j < 50; ++j)
            v = fmaf(acc[j], w_spek[j * 5 + t], v);
        s[t] = v;
    }
    float pan = s[4];
#pragma unroll
    for (int c = 0; c < 4; ++c)
        pan = fmaf(hrhs[((b * 4 + c) * HRR + h) * HRR + w], s[c], pan);
    out_pan[p] = pan;

    // spak head (4) at subsampled positions -> INV (3 unique entries)
    if ((h & 3) == 1 && (w & 3) == 1) {
        float v[4];
#pragma unroll
        for (int t = 0; t < 4; ++t) {
            float x = b_spak[t];
#pragma unroll
            for (int j = 0; j < 50; ++j)
                x = fmaf(acc[j], w_spak[j * 4 + t], x);
            v[t] = x;
        }
        // m = [[v0, 0], [v2, v3]];  INV = m^T m
        const float I00 = v[0] * v[0] + v[2] * v[2];
        const float I01 = v[2] * v[3];
        const float I11 = v[3] * v[3];
        const int hh = h >> 2, ww = w >> 2;
        const int o = ((b * LSZ + hh) * LSZ + ww) * 3;
        inv_ws[o + 0] = I00;
        inv_ws[o + 1] = I01;
        inv_ws[o + 2] = I11;
    }
}

// ---------------------------------------------------------------------------
// Kernel 2: pre_msi. One thread per (b, c, hh, ww). Recomputes the 225
// Gaussian weights in-register; normalization folded into final divide.
// ---------------------------------------------------------------------------
__global__ __launch_bounds__(256) void msi_kernel(
    const float* __restrict__ hrhs, const float* __restrict__ inv_ws,
    float* __restrict__ out_msi)    // B*4*64*64 floats
{
    const int t  = blockIdx.x * blockDim.x + threadIdx.x;  // 0..131071
    const int ww = t & 63;
    const int hh = (t >> 6) & 63;
    const int c  = (t >> 12) & 3;
    const int b  = t >> 14;

    const int o = ((b * LSZ + hh) * LSZ + ww) * 3;
    const float I00 = inv_ws[o + 0];
    const float I01 = inv_ws[o + 1];
    const float I11 = inv_ws[o + 2];

    const float* plane = hrhs + (size_t)(b * 4 + c) * HRR * HRR;

    float accv = 0.0f, wsum = 0.0f;
#pragma unroll
    for (int p = 0; p < KK; ++p) {
        const int   r  = 4 * hh + p - 6;
        const float dp = (float)(p - 7);
        const bool  rok = (unsigned)r < (unsigned)HRR;
#pragma unroll
        for (int q = 0; q < KK; ++q) {
            const int   sc = 4 * ww + q - 6;
            const float dq = (float)(q - 7);
            const float tt = fmaf(I00 * dp, dp,
                              fmaf(2.0f * I01 * dp, dq, I11 * dq * dq));
            const float e = __expf(-0.5f * tt);
            wsum += e;
            const float x = (rok && (unsigned)sc < (unsigned)HRR)
                                ? plane[r * HRR + sc] : 0.0f;
            accv = fmaf(x, e, accv);
        }
    }
    out_msi[t] = accv / wsum;
}

extern "C" void kernel_launch(void* const* d_in, const int* in_sizes, int n_in,
                              void* d_out, int out_size, void* d_ws, size_t ws_size,
                              hipStream_t stream) {
    const float* coords = (const float*)d_in[0];
    const float* hrhs   = (const float*)d_in[1];
    const float* w1     = (const float*)d_in[2];
    const float* b1     = (const float*)d_in[3];
    const float* w2     = (const float*)d_in[4];
    const float* b2     = (const float*)d_in[5];
    const float* w_spek = (const float*)d_in[6];
    const float* b_spek = (const float*)d_in[7];
    const float* w_spak = (const float*)d_in[8];
    const float* b_spak = (const float*)d_in[9];

    float* out      = (float*)d_out;
    float* out_msi  = out;                       // 8*4*64*64  = 131072
    float* out_pan  = out + 8 * 4 * 64 * 64;     // 8*1*256*256 = 524288
    float* inv_ws   = (float*)d_ws;              // 8*64*64*3 floats = 393 KB

    const int n_pts = 8 * HRR * HRR;             // 524288
    mlp_kernel<<<n_pts / 256, 256, 0, stream>>>(
        coords, hrhs, w1, b1, w2, b2, w_spek, b_spek, w_spak, b_spak,
        out_pan, inv_ws);

    const int n_msi = 8 * 4 * LSZ * LSZ;         // 131072
    msi_kernel<<<n_msi / 256, 256, 0, stream>>>(hrhs, inv_ws, out_msi);
}

// Round 2
// 77.234 us; speedup vs baseline: 1.9505x; 1.9505x over previous
//
#include <hip/hip_runtime.h>

#define HRR 256
#define LSZ 64
#define KK  15

typedef _Float16 half8 __attribute__((ext_vector_type(8)));
typedef float    f32x16 __attribute__((ext_vector_type(16)));

// ---------------------------------------------------------------------------
// Prep: pack W2 [200x50] fp32 -> f16 in B-fragment order for
// v_mfma_f32_32x32x16_f16:  [ct(2)][kt(14)][lane(64)][i(8)]
//   col = ct*32 + (lane&31), k = kt*16 + (lane>>5)*8 + i, zero-padded.
// ---------------------------------------------------------------------------
__global__ void pack_w2_kernel(const float* __restrict__ w2,
                               _Float16* __restrict__ out)
{
    int flat = blockIdx.x * 256 + threadIdx.x;   // 0..14335
    if (flat >= 14336) return;
    int ct = flat / 7168;
    int r  = flat % 7168;
    int kt = r / 512;
    int r2 = r % 512;
    int ln = r2 / 8;
    int i  = r2 % 8;
    int col = ct * 32 + (ln & 31);
    int k   = kt * 16 + (ln >> 5) * 8 + i;
    float v = (col < 50 && k < 200) ? w2[k * 50 + col] : 0.0f;
    out[flat] = (_Float16)v;
}

// ---------------------------------------------------------------------------
// Main: per-block 256 points. Layer-1 on VALU -> A-frags in LDS (dbuf),
// layer-2 via MFMA f16 (32x32x16), heads/pan/INV per-thread epilogue.
// ---------------------------------------------------------------------------
__global__ __launch_bounds__(256, 2) void mlp2_kernel(
    const float* __restrict__ coords, const float* __restrict__ hrhs,
    const float* __restrict__ w1,     const float* __restrict__ b1,
    const _Float16* __restrict__ w2p, const float* __restrict__ b2,
    const float* __restrict__ w_spek, const float* __restrict__ b_spek,
    const float* __restrict__ w_spak, const float* __restrict__ b_spak,
    float* __restrict__ out_pan,      float* __restrict__ inv_ws)
{
    __shared__ __align__(16) unsigned char smem[61440];
    _Float16* Bf = (_Float16*)smem;             // [2][14][64][8]  = 28672 B
    _Float16* Ab = (_Float16*)(smem + 28672);   // [2][8][2][64][8] = 32768 B
    _Float16* F  = (_Float16*)smem;             // [256][72] f16 (reuses B+A)

    const int tid  = threadIdx.x;
    const int lane = tid & 63;
    const int wv   = tid >> 6;
    const int p0   = blockIdx.x * 256;

    // ---- stage W2 B-fragments into LDS (28672 B) ----
    {
        const uint4* src = (const uint4*)w2p;
        uint4* dst = (uint4*)Bf;
        #pragma unroll
        for (int it = 0; it < 7; ++it)
            dst[it * 256 + tid] = src[it * 256 + tid];
    }

    // ---- thread-constant layer-1 fill parameters ----
    const int kth = (tid >> 6) & 1;   // which k-16 half of the K=32 step
    const int rt0 = tid >> 7;         // row-tile parity
    const int koq = (tid >> 5) & 1;   // k-octet within frag (== lane>>5)

    float c0v[4], c1v[4];
    #pragma unroll
    for (int j = 0; j < 4; ++j) {
        int row = (rt0 + 2 * j) * 32 + (tid & 31);
        float2 cc = ((const float2*)coords)[p0 + row];
        c0v[j] = cc.x; c1v[j] = cc.y;
    }

    // ---- accumulators, bias folded in (f = H@W2 + b2) ----
    const int colA = lane & 31;
    const float bias0 = b2[colA];                                  // col < 32
    const float bias1 = (colA + 32 < 50) ? b2[colA + 32] : 0.0f;   // col 32..63
    f32x16 acc00, acc01, acc10, acc11;
    #pragma unroll
    for (int r = 0; r < 16; ++r) {
        acc00[r] = bias0; acc10[r] = bias0;
        acc01[r] = bias1; acc11[r] = bias1;
    }

    // layer-1: compute h1 for 4 row-tiles x 8 k, write A-frag layout
    auto fill = [&](int ks, int buf) {
        const int kb = ks * 32 + kth * 16 + koq * 8;
        float wa[8] = {0,0,0,0,0,0,0,0};
        float wb[8] = {0,0,0,0,0,0,0,0};
        float bv[8] = {0,0,0,0,0,0,0,0};
        if (kb < 200) {
            float4 x0 = *(const float4*)(w1 + kb);
            float4 x1 = *(const float4*)(w1 + kb + 4);
            float4 y0 = *(const float4*)(w1 + 200 + kb);
            float4 y1 = *(const float4*)(w1 + 200 + kb + 4);
            float4 z0 = *(const float4*)(b1 + kb);
            float4 z1 = *(const float4*)(b1 + kb + 4);
            wa[0]=x0.x; wa[1]=x0.y; wa[2]=x0.z; wa[3]=x0.w;
            wa[4]=x1.x; wa[5]=x1.y; wa[6]=x1.z; wa[7]=x1.w;
            wb[0]=y0.x; wb[1]=y0.y; wb[2]=y0.z; wb[3]=y0.w;
            wb[4]=y1.x; wb[5]=y1.y; wb[6]=y1.z; wb[7]=y1.w;
            bv[0]=z0.x; bv[1]=z0.y; bv[2]=z0.z; bv[3]=z0.w;
            bv[4]=z1.x; bv[5]=z1.y; bv[6]=z1.z; bv[7]=z1.w;
        }
        #pragma unroll
        for (int j = 0; j < 4; ++j) {
            half8 hv;
            #pragma unroll
            for (int i = 0; i < 8; ++i) {
                float h = fmaf(c0v[j], wa[i], fmaf(c1v[j], wb[i], bv[i]));
                hv[i] = (_Float16)fmaxf(h, 0.0f);
            }
            int rt = rt0 + 2 * j;
            *(half8*)(Ab + (size_t)(((((buf << 3) + rt) << 1) + kth) * 512 + lane * 8)) = hv;
        }
    };

    // one K=32 MFMA step for this wave's 64x64 tile
    auto step = [&](int ks, int buf) {
        #pragma unroll
        for (int kt2 = 0; kt2 < 2; ++kt2) {
            half8 a0 = *(const half8*)(Ab + (size_t)(((((buf << 3) + 2*wv    ) << 1) + kt2) * 512 + lane * 8));
            half8 a1 = *(const half8*)(Ab + (size_t)(((((buf << 3) + 2*wv + 1) << 1) + kt2) * 512 + lane * 8));
            half8 bq0 = *(const half8*)(Bf + (size_t)(        (ks * 2 + kt2) * 512 + lane * 8));
            half8 bq1 = *(const half8*)(Bf + (size_t)(7168 + (ks * 2 + kt2) * 512 + lane * 8));
            acc00 = __builtin_amdgcn_mfma_f32_32x32x16_f16(a0, bq0, acc00, 0, 0, 0);
            acc01 = __builtin_amdgcn_mfma_f32_32x32x16_f16(a0, bq1, acc01, 0, 0, 0);
            acc10 = __builtin_amdgcn_mfma_f32_32x32x16_f16(a1, bq0, acc10, 0, 0, 0);
            acc11 = __builtin_amdgcn_mfma_f32_32x32x16_f16(a1, bq1, acc11, 0, 0, 0);
        }
    };

    fill(0, 0);
    __syncthreads();
    for (int ks = 0; ks < 7; ++ks) {
        if (ks < 6) fill(ks + 1, (ks + 1) & 1);
        step(ks, ks & 1);
        __syncthreads();
    }

    // ---- write F = relu(acc) to LDS row-major [256][72] f16 ----
    {
        const int rq = 4 * (lane >> 5);
        #pragma unroll
        for (int rt = 0; rt < 2; ++rt) {
            #pragma unroll
            for (int ct = 0; ct < 2; ++ct) {
                const f32x16& A = (rt == 0) ? (ct == 0 ? acc00 : acc01)
                                            : (ct == 0 ? acc10 : acc11);
                int rowb = wv * 64 + rt * 32 + rq;
                int col  = ct * 32 + colA;
                #pragma unroll
                for (int r = 0; r < 16; ++r) {
                    int row = rowb + (r & 3) + 8 * (r >> 2);
                    F[row * 72 + col] = (_Float16)fmaxf(A[r], 0.0f);
                }
            }
        }
    }
    __syncthreads();

    // ---- per-thread epilogue: heads, pan, INV ----
    {
        float s[9];
        #pragma unroll
        for (int t = 0; t < 5; ++t) s[t] = b_spek[t];
        #pragma unroll
        for (int t = 0; t < 4; ++t) s[5 + t] = b_spak[t];

        const _Float16* Fr = F + tid * 72;
        #pragma unroll
        for (int q = 0; q < 7; ++q) {
            half8 hv = *(const half8*)(Fr + q * 8);
            #pragma unroll
            for (int i = 0; i < 8; ++i) {
                const int j = q * 8 + i;
                if (j < 50) {
                    float v = (float)hv[i];
                    #pragma unroll
                    for (int t = 0; t < 5; ++t) s[t]     = fmaf(v, w_spek[j * 5 + t], s[t]);
                    #pragma unroll
                    for (int t = 0; t < 4; ++t) s[5 + t] = fmaf(v, w_spak[j * 4 + t], s[5 + t]);
                }
            }
        }

        const int p   = p0 + tid;
        const int b   = p >> 16;
        const int idx = p & 65535;
        const int h   = idx >> 8;
        const int w   = idx & 255;

        float pan = s[4];
        #pragma unroll
        for (int c = 0; c < 4; ++c)
            pan = fmaf(hrhs[((b * 4 + c) * HRR + h) * HRR + w], s[c], pan);
        out_pan[p] = pan;

        if ((h & 3) == 1 && (w & 3) == 1) {
            const float v0 = s[5], v2 = s[7], v3 = s[8];
            const float I00 = v0 * v0 + v2 * v2;
            const float I01 = v2 * v3;
            const float I11 = v3 * v3;
            const int hh = h >> 2, ww = w >> 2;
            const int o = ((b * LSZ + hh) * LSZ + ww) * 3;
            inv_ws[o + 0] = I00;
            inv_ws[o + 1] = I01;
            inv_ws[o + 2] = I11;
        }
    }
}

// ---------------------------------------------------------------------------
// Kernel 2: pre_msi (unchanged from round 1).
// ---------------------------------------------------------------------------
__global__ __launch_bounds__(256) void msi_kernel(
    const float* __restrict__ hrhs, const float* __restrict__ inv_ws,
    float* __restrict__ out_msi)
{
    const int t  = blockIdx.x * blockDim.x + threadIdx.x;  // 0..131071
    const int ww = t & 63;
    const int hh = (t >> 6) & 63;
    const int c  = (t >> 12) & 3;
    const int b  = t >> 14;

    const int o = ((b * LSZ + hh) * LSZ + ww) * 3;
    const float I00 = inv_ws[o + 0];
    const float I01 = inv_ws[o + 1];
    const float I11 = inv_ws[o + 2];

    const float* plane = hrhs + (size_t)(b * 4 + c) * HRR * HRR;

    float accv = 0.0f, wsum = 0.0f;
    #pragma unroll
    for (int p = 0; p < KK; ++p) {
        const int   r  = 4 * hh + p - 6;
        const float dp = (float)(p - 7);
        const bool  rok = (unsigned)r < (unsigned)HRR;
        #pragma unroll
        for (int q = 0; q < KK; ++q) {
            const int   sc = 4 * ww + q - 6;
            const float dq = (float)(q - 7);
            const float tt = fmaf(I00 * dp, dp,
                              fmaf(2.0f * I01 * dp, dq, I11 * dq * dq));
            const float e = __expf(-0.5f * tt);
            wsum += e;
            const float x = (rok && (unsigned)sc < (unsigned)HRR)
                                ? plane[r * HRR + sc] : 0.0f;
            accv = fmaf(x, e, accv);
        }
    }
    out_msi[t] = accv / wsum;
}

extern "C" void kernel_launch(void* const* d_in, const int* in_sizes, int n_in,
                              void* d_out, int out_size, void* d_ws, size_t ws_size,
                              hipStream_t stream) {
    const float* coords = (const float*)d_in[0];
    const float* hrhs   = (const float*)d_in[1];
    const float* w1     = (const float*)d_in[2];
    const float* b1     = (const float*)d_in[3];
    const float* w2     = (const float*)d_in[4];
    const float* b2     = (const float*)d_in[5];
    const float* w_spek = (const float*)d_in[6];
    const float* b_spek = (const float*)d_in[7];
    const float* w_spak = (const float*)d_in[8];
    const float* b_spak = (const float*)d_in[9];

    float* out     = (float*)d_out;
    float* out_msi = out;                        // 8*4*64*64   = 131072
    float* out_pan = out + 8 * 4 * 64 * 64;      // 8*1*256*256 = 524288

    float*     inv_ws = (float*)d_ws;                         // 393216 B
    _Float16*  w2p    = (_Float16*)((char*)d_ws + 393216);    // 28672 B

    pack_w2_kernel<<<56, 256, 0, stream>>>(w2, w2p);

    mlp2_kernel<<<2048, 256, 0, stream>>>(
        coords, hrhs, w1, b1, w2p, b2, w_spek, b_spek, w_spak, b_spak,
        out_pan, inv_ws);

    const int n_msi = 8 * 4 * LSZ * LSZ;         // 131072
    msi_kernel<<<n_msi / 256, 256, 0, stream>>>(hrhs, inv_ws, out_msi);
}

// Round 4
// 62.947 us; speedup vs baseline: 2.3932x; 1.2270x over previous
//
#include <hip/hip_runtime.h>

#define HRR 256
#define LSZ 64
#define KK  15

typedef _Float16 half8  __attribute__((ext_vector_type(8)));
typedef __fp16   fp16x2 __attribute__((ext_vector_type(2)));
typedef float    f32x16 __attribute__((ext_vector_type(16)));

// ---------------------------------------------------------------------------
// Pack kernel.
//  w2p: W2^T A-frags for v_mfma_f32_32x32x16_f16, [rt(2)][f(14)][lane(64)][i(8)]
//       row j = rt*32 + (lane&31), k = f*16 + (lane>>5)*8 + i
//       k<200 -> W2[k][j]; k==200 -> b2[j] (bias folded as extra K-row); else 0
//  whp: head-weight A-frags [f(4)][lane(64)][i(8)]
//       row t = lane&31 (0..4 spek, 5..8 spak), k = f-dim
//       k<50 -> Wh[k][t]; k==50 -> head bias (F-row 50 forced to 1); else 0
// ---------------------------------------------------------------------------
__global__ __launch_bounds__(256) void pack_kernel(
    const float* __restrict__ w2,     const float* __restrict__ b2,
    const float* __restrict__ w_spek, const float* __restrict__ b_spek,
    const float* __restrict__ w_spak, const float* __restrict__ b_spak,
    _Float16* __restrict__ w2p,       _Float16* __restrict__ whp)
{
    int flat = blockIdx.x * 256 + threadIdx.x;
    if (flat < 14336) {
        int rt = flat / 7168;
        int rem = flat % 7168;
        int f  = rem / 512;
        int r2 = rem % 512;
        int ln = r2 / 8;
        int i  = r2 % 8;
        int j = rt * 32 + (ln & 31);
        int k = f * 16 + (ln >> 5) * 8 + i;
        float v = 0.0f;
        if (j < 50) {
            if (k < 200)       v = w2[k * 50 + j];
            else if (k == 200) v = b2[j];
        }
        w2p[flat] = (_Float16)v;
    } else if (flat < 14336 + 2048) {
        int r  = flat - 14336;
        int f  = r / 512;
        int r2 = r % 512;
        int ln = r2 / 8;
        int i  = r2 % 8;
        int t = ln & 31;
        int k = f * 16 + (ln >> 5) * 8 + i;
        float v = 0.0f;
        if (t < 9) {
            if (k < 50)       v = (t < 5) ? w_spek[k * 5 + t] : w_spak[k * 4 + (t - 5)];
            else if (k == 50) v = (t < 5) ? b_spek[t] : b_spak[t - 5];
        }
        whp[r] = (_Float16)v;
    }
}

// ---------------------------------------------------------------------------
// Main kernel. 4 waves/block, each wave owns 64 points, fully barrier-free
// after one W2 staging sync. Computes F^T = W2^T @ H^T via MFMA (H^T built
// in-register), then heads^T = Wh^T @ F^T via a second in-register MFMA.
// ---------------------------------------------------------------------------
__global__ __launch_bounds__(256) void mlp3_kernel(
    const float* __restrict__ coords, const float* __restrict__ hrhs,
    const float* __restrict__ w1,     const float* __restrict__ b1,
    const _Float16* __restrict__ w2p, const _Float16* __restrict__ whp,
    float* __restrict__ out_pan,      float* __restrict__ inv_ws)
{
    __shared__ __align__(16) _Float16 W2s[14336];   // 28672 B

    const int tid  = threadIdx.x;
    const int lane = tid & 63;
    const int wv   = tid >> 6;
    const int hl   = lane >> 5;     // half-wave index
    const int cl   = lane & 31;

    // ---- stage W2^T A-frags into LDS (one barrier total) ----
    {
        const uint4* src = (const uint4*)w2p;
        uint4* dst = (uint4*)W2s;
        #pragma unroll
        for (int it = 0; it < 7; ++it)
            dst[it * 256 + tid] = src[it * 256 + tid];
    }
    __syncthreads();

    const int p0 = blockIdx.x * 256 + wv * 64;

    // coords of the two point-columns this lane serves
    const float2 cA = ((const float2*)coords)[p0 + cl];        // ct = 0
    const float2 cB = ((const float2*)coords)[p0 + 32 + cl];   // ct = 1

    f32x16 acc00, acc01, acc10, acc11;
    #pragma unroll
    for (int r = 0; r < 16; ++r) { acc00[r] = 0.f; acc01[r] = 0.f; acc10[r] = 0.f; acc11[r] = 0.f; }

    // one 32x32x16 step: A from LDS, B (= H^T) built in-register
    auto step = [&](int ks, int kt) {
        const int f = ks * 2 + kt;
        half8 a0 = *(const half8*)(W2s + f * 512 + lane * 8);
        half8 a1 = *(const half8*)(W2s + (14 + f) * 512 + lane * 8);
        const int kb = ks * 32 + kt * 16 + hl * 8;
        union { half8 h; fp16x2 p[4]; uint32_t u[4]; } B0, B1;
        if (kb < 200) {
            const float4 x0 = *(const float4*)(w1 + kb);
            const float4 x1 = *(const float4*)(w1 + kb + 4);
            const float4 y0 = *(const float4*)(w1 + 200 + kb);
            const float4 y1 = *(const float4*)(w1 + 200 + kb + 4);
            const float4 z0 = *(const float4*)(b1 + kb);
            const float4 z1 = *(const float4*)(b1 + kb + 4);
            const float wa[8] = {x0.x,x0.y,x0.z,x0.w,x1.x,x1.y,x1.z,x1.w};
            const float wb[8] = {y0.x,y0.y,y0.z,y0.w,y1.x,y1.y,y1.z,y1.w};
            const float bv[8] = {z0.x,z0.y,z0.z,z0.w,z1.x,z1.y,z1.z,z1.w};
            float hA[8], hB[8];
            #pragma unroll
            for (int i = 0; i < 8; ++i) {
                hA[i] = fmaxf(fmaf(cA.x, wa[i], fmaf(cA.y, wb[i], bv[i])), 0.f);
                hB[i] = fmaxf(fmaf(cB.x, wa[i], fmaf(cB.y, wb[i], bv[i])), 0.f);
            }
            #pragma unroll
            for (int m = 0; m < 4; ++m) {
                B0.p[m] = __builtin_amdgcn_cvt_pkrtz(hA[2*m], hA[2*m+1]);
                B1.p[m] = __builtin_amdgcn_cvt_pkrtz(hB[2*m], hB[2*m+1]);
            }
        } else {
            #pragma unroll
            for (int m = 0; m < 4; ++m) { B0.u[m] = 0u; B1.u[m] = 0u; }
            if (kb == 200) { B0.u[0] = 0x3C00u; B1.u[0] = 0x3C00u; }  // ones row (bias)
        }
        acc00 = __builtin_amdgcn_mfma_f32_32x32x16_f16(a0, B0.h, acc00, 0, 0, 0);
        acc01 = __builtin_amdgcn_mfma_f32_32x32x16_f16(a0, B1.h, acc01, 0, 0, 0);
        acc10 = __builtin_amdgcn_mfma_f32_32x32x16_f16(a1, B0.h, acc10, 0, 0, 0);
        acc11 = __builtin_amdgcn_mfma_f32_32x32x16_f16(a1, B1.h, acc11, 0, 0, 0);
    };

    for (int ks = 0; ks < 6; ++ks) { step(ks, 0); step(ks, 1); }
    step(6, 0);   // contains k=200 ones-row; f=13 slice is all-zero -> skipped

    // ---- relu + pack F^T to f16 pairs:  pk{rt}[ct][m] covers rows
    //      rt*32 + 8*(m>>1) + 4*hl + 2*(m&1) .. +1 of point ct*32+cl ----
    uint32_t pk0[2][8], pk1[2][8];
    #pragma unroll
    for (int m = 0; m < 8; ++m) {
        union { fp16x2 p; uint32_t u; } q;
        q.p = __builtin_amdgcn_cvt_pkrtz(fmaxf(acc00[2*m], 0.f), fmaxf(acc00[2*m+1], 0.f));
        pk0[0][m] = q.u;
        q.p = __builtin_amdgcn_cvt_pkrtz(fmaxf(acc01[2*m], 0.f), fmaxf(acc01[2*m+1], 0.f));
        pk0[1][m] = q.u;
        q.p = __builtin_amdgcn_cvt_pkrtz(fmaxf(acc10[2*m], 0.f), fmaxf(acc10[2*m+1], 0.f));
        pk1[0][m] = q.u;
        q.p = __builtin_amdgcn_cvt_pkrtz(fmaxf(acc11[2*m], 0.f), fmaxf(acc11[2*m+1], 0.f));
        pk1[1][m] = q.u;
    }
    // force F-row 50 = 1.0 (head-bias row); rows 50,51 live in pk1[ct][5] of hl==0
    if (hl == 0) { pk1[0][5] = 0x3C00u; pk1[1][5] = 0x3C00u; }

    // ---- head GEMM: heads^T = Wh^T @ F^T (K = 64, 4 kt-steps) ----
    f32x16 acch0, acch1;
    #pragma unroll
    for (int r = 0; r < 16; ++r) { acch0[r] = 0.f; acch1[r] = 0.f; }

    #pragma unroll
    for (int kt = 0; kt < 4; ++kt) {
        half8 ah = *(const half8*)(whp + kt * 512 + lane * 8);
        const int bb = 4 * (kt & 1);
        #pragma unroll
        for (int ct = 0; ct < 2; ++ct) {
            const uint32_t e0 = (kt < 2) ? pk0[ct][bb + 0] : pk1[ct][bb + 0];
            const uint32_t e1 = (kt < 2) ? pk0[ct][bb + 1] : pk1[ct][bb + 1];
            const uint32_t e2 = (kt < 2) ? pk0[ct][bb + 2] : pk1[ct][bb + 2];
            const uint32_t e3 = (kt < 2) ? pk0[ct][bb + 3] : pk1[ct][bb + 3];
            const uint32_t o0 = hl ? e2 : e0;   // own rows 16kt+8hl+{0,1}... (use)
            const uint32_t o1 = hl ? e3 : e1;
            const uint32_t s0 = hl ? e0 : e2;   // what the partner needs
            const uint32_t s1 = hl ? e1 : e3;
            const uint32_t g0 = (uint32_t)__shfl_xor((int)s0, 32);
            const uint32_t g1 = (uint32_t)__shfl_xor((int)s1, 32);
            union { half8 h; uint32_t u[4]; } BF;
            BF.u[0] = hl ? g0 : o0;
            BF.u[1] = hl ? g1 : o1;
            BF.u[2] = hl ? o0 : g0;
            BF.u[3] = hl ? o1 : g1;
            if (ct == 0) acch0 = __builtin_amdgcn_mfma_f32_32x32x16_f16(ah, BF.h, acch0, 0, 0, 0);
            else         acch1 = __builtin_amdgcn_mfma_f32_32x32x16_f16(ah, BF.h, acch1, 0, 0, 0);
        }
    }

    // ---- gather all 9 head values for this lane's point (p = p0 + lane) ----
    float s[9];
    #pragma unroll
    for (int r = 0; r < 4; ++r) {
        const float own  = hl ? acch1[r] : acch0[r];
        const float send = hl ? acch0[r] : acch1[r];
        const float got  = __shfl_xor(send, 32);
        s[r]     = hl ? got : own;   // t = 0..3
        s[4 + r] = hl ? own : got;   // t = 4..7
    }
    {
        const float own  = hl ? acch1[4] : acch0[4];
        const float send = hl ? acch0[4] : acch1[4];
        const float got  = __shfl_xor(send, 32);
        s[8] = hl ? got : own;       // t = 8
    }

    // ---- pan, INV, stores ----
    const int p   = p0 + lane;
    const int b   = p >> 16;
    const int pix = p & 65535;
    const int ph  = pix >> 8;
    const int pw  = pix & 255;

    float pan = s[4];
    #pragma unroll
    for (int c = 0; c < 4; ++c)
        pan = fmaf(hrhs[((b * 4 + c) << 16) + pix], s[c], pan);
    out_pan[p] = pan;

    if ((ph & 3) == 1 && (pw & 3) == 1) {
        const float v0 = s[5], v2 = s[7], v3 = s[8];
        const int hh = ph >> 2, ww = pw >> 2;
        const int o = ((b * LSZ + hh) * LSZ + ww) * 3;
        inv_ws[o + 0] = v0 * v0 + v2 * v2;
        inv_ws[o + 1] = v2 * v3;
        inv_ws[o + 2] = v3 * v3;
    }
}

// ---------------------------------------------------------------------------
// Kernel 2: pre_msi (unchanged from round 2).
// ---------------------------------------------------------------------------
__global__ __launch_bounds__(256) void msi_kernel(
    const float* __restrict__ hrhs, const float* __restrict__ inv_ws,
    float* __restrict__ out_msi)
{
    const int t  = blockIdx.x * blockDim.x + threadIdx.x;  // 0..131071
    const int ww = t & 63;
    const int hh = (t >> 6) & 63;
    const int c  = (t >> 12) & 3;
    const int b  = t >> 14;

    const int o = ((b * LSZ + hh) * LSZ + ww) * 3;
    const float I00 = inv_ws[o + 0];
    const float I01 = inv_ws[o + 1];
    const float I11 = inv_ws[o + 2];

    const float* plane = hrhs + (size_t)(b * 4 + c) * HRR * HRR;

    float accv = 0.0f, wsum = 0.0f;
    #pragma unroll
    for (int p = 0; p < KK; ++p) {
        const int   r  = 4 * hh + p - 6;
        const float dp = (float)(p - 7);
        const bool  rok = (unsigned)r < (unsigned)HRR;
        #pragma unroll
        for (int q = 0; q < KK; ++q) {
            const int   sc = 4 * ww + q - 6;
            const float dq = (float)(q - 7);
            const float tt = fmaf(I00 * dp, dp,
                              fmaf(2.0f * I01 * dp, dq, I11 * dq * dq));
            const float e = __expf(-0.5f * tt);
            wsum += e;
            const float x = (rok && (unsigned)sc < (unsigned)HRR)
                                ? plane[r * HRR + sc] : 0.0f;
            accv = fmaf(x, e, accv);
        }
    }
    out_msi[t] = accv / wsum;
}

extern "C" void kernel_launch(void* const* d_in, const int* in_sizes, int n_in,
                              void* d_out, int out_size, void* d_ws, size_t ws_size,
                              hipStream_t stream) {
    const float* coords = (const float*)d_in[0];
    const float* hrhs   = (const float*)d_in[1];
    const float* w1     = (const float*)d_in[2];
    const float* b1     = (const float*)d_in[3];
    const float* w2     = (const float*)d_in[4];
    const float* b2     = (const float*)d_in[5];
    const float* w_spek = (const float*)d_in[6];
    const float* b_spek = (const float*)d_in[7];
    const float* w_spak = (const float*)d_in[8];
    const float* b_spak = (const float*)d_in[9];

    float* out     = (float*)d_out;
    float* out_msi = out;                        // 8*4*64*64   = 131072
    float* out_pan = out + 8 * 4 * 64 * 64;      // 8*1*256*256 = 524288

    float*     inv_ws = (float*)d_ws;                         // 393216 B
    _Float16*  w2p    = (_Float16*)((char*)d_ws + 393216);    // 28672 B
    _Float16*  whp    = (_Float16*)((char*)d_ws + 421888);    // 4096 B

    pack_kernel<<<64, 256, 0, stream>>>(w2, b2, w_spek, b_spek, w_spak, b_spak,
                                        w2p, whp);

    mlp3_kernel<<<2048, 256, 0, stream>>>(
        coords, hrhs, w1, b1, w2p, whp, out_pan, inv_ws);

    const int n_msi = 8 * 4 * LSZ * LSZ;         // 131072
    msi_kernel<<<n_msi / 256, 256, 0, stream>>>(hrhs, inv_ws, out_msi);
}

// Round 5
// 53.373 us; speedup vs baseline: 2.8225x; 1.1794x over previous
//
#include <hip/hip_runtime.h>

#define HRR 256
#define LSZ 64
#define KK  15
#define PROWS 267
#define PCOLS 272

typedef _Float16 half8  __attribute__((ext_vector_type(8)));
typedef __fp16   fp16x2 __attribute__((ext_vector_type(2)));
typedef float    f32x16 __attribute__((ext_vector_type(16)));

// ---------------------------------------------------------------------------
// Pack kernel (unchanged from round 4).
// ---------------------------------------------------------------------------
__global__ __launch_bounds__(256) void pack_kernel(
    const float* __restrict__ w2,     const float* __restrict__ b2,
    const float* __restrict__ w_spek, const float* __restrict__ b_spek,
    const float* __restrict__ w_spak, const float* __restrict__ b_spak,
    _Float16* __restrict__ w2p,       _Float16* __restrict__ whp)
{
    int flat = blockIdx.x * 256 + threadIdx.x;
    if (flat < 14336) {
        int rt = flat / 7168;
        int rem = flat % 7168;
        int f  = rem / 512;
        int r2 = rem % 512;
        int ln = r2 / 8;
        int i  = r2 % 8;
        int j = rt * 32 + (ln & 31);
        int k = f * 16 + (ln >> 5) * 8 + i;
        float v = 0.0f;
        if (j < 50) {
            if (k < 200)       v = w2[k * 50 + j];
            else if (k == 200) v = b2[j];
        }
        w2p[flat] = (_Float16)v;
    } else if (flat < 14336 + 2048) {
        int r  = flat - 14336;
        int f  = r / 512;
        int r2 = r % 512;
        int ln = r2 / 8;
        int i  = r2 % 8;
        int t = ln & 31;
        int k = f * 16 + (ln >> 5) * 8 + i;
        float v = 0.0f;
        if (t < 9) {
            if (k < 50)       v = (t < 5) ? w_spek[k * 5 + t] : w_spak[k * 4 + (t - 5)];
            else if (k == 50) v = (t < 5) ? b_spek[t] : b_spak[t - 5];
        }
        whp[r] = (_Float16)v;
    }
}

// ---------------------------------------------------------------------------
// Pad kernel: zero-padded hrhs copy [32][PROWS][PCOLS], pad[pr][pc] =
// hrhs[pr-6][pc-6] (zeros outside). Enables unconditional aligned float4
// gathers in msi2.
// ---------------------------------------------------------------------------
__global__ __launch_bounds__(256) void pad_kernel(
    const float* __restrict__ hrhs, float* __restrict__ pad)
{
    int i = blockIdx.x * 256 + threadIdx.x;     // 0 .. 32*PROWS*PCOLS-1
    int pc   = i % PCOLS;
    int rest = i / PCOLS;
    int pr   = rest % PROWS;
    int bc   = rest / PROWS;
    int r   = pr - 6;
    int col = pc - 6;
    float v = ((unsigned)r < 256u && (unsigned)col < 256u)
                  ? hrhs[(bc << 16) + (r << 8) + col] : 0.0f;
    pad[i] = v;
}

// ---------------------------------------------------------------------------
// Main MLP kernel (unchanged from round 4).
// ---------------------------------------------------------------------------
__global__ __launch_bounds__(256) void mlp3_kernel(
    const float* __restrict__ coords, const float* __restrict__ hrhs,
    const float* __restrict__ w1,     const float* __restrict__ b1,
    const _Float16* __restrict__ w2p, const _Float16* __restrict__ whp,
    float* __restrict__ out_pan,      float* __restrict__ inv_ws)
{
    __shared__ __align__(16) _Float16 W2s[14336];   // 28672 B

    const int tid  = threadIdx.x;
    const int lane = tid & 63;
    const int wv   = tid >> 6;
    const int hl   = lane >> 5;     // half-wave index
    const int cl   = lane & 31;

    {
        const uint4* src = (const uint4*)w2p;
        uint4* dst = (uint4*)W2s;
        #pragma unroll
        for (int it = 0; it < 7; ++it)
            dst[it * 256 + tid] = src[it * 256 + tid];
    }
    __syncthreads();

    const int p0 = blockIdx.x * 256 + wv * 64;

    const float2 cA = ((const float2*)coords)[p0 + cl];        // ct = 0
    const float2 cB = ((const float2*)coords)[p0 + 32 + cl];   // ct = 1

    f32x16 acc00, acc01, acc10, acc11;
    #pragma unroll
    for (int r = 0; r < 16; ++r) { acc00[r] = 0.f; acc01[r] = 0.f; acc10[r] = 0.f; acc11[r] = 0.f; }

    auto step = [&](int ks, int kt) {
        const int f = ks * 2 + kt;
        half8 a0 = *(const half8*)(W2s + f * 512 + lane * 8);
        half8 a1 = *(const half8*)(W2s + (14 + f) * 512 + lane * 8);
        const int kb = ks * 32 + kt * 16 + hl * 8;
        union { half8 h; fp16x2 p[4]; uint32_t u[4]; } B0, B1;
        if (kb < 200) {
            const float4 x0 = *(const float4*)(w1 + kb);
            const float4 x1 = *(const float4*)(w1 + kb + 4);
            const float4 y0 = *(const float4*)(w1 + 200 + kb);
            const float4 y1 = *(const float4*)(w1 + 200 + kb + 4);
            const float4 z0 = *(const float4*)(b1 + kb);
            const float4 z1 = *(const float4*)(b1 + kb + 4);
            const float wa[8] = {x0.x,x0.y,x0.z,x0.w,x1.x,x1.y,x1.z,x1.w};
            const float wb[8] = {y0.x,y0.y,y0.z,y0.w,y1.x,y1.y,y1.z,y1.w};
            const float bv[8] = {z0.x,z0.y,z0.z,z0.w,z1.x,z1.y,z1.z,z1.w};
            float hA[8], hB[8];
            #pragma unroll
            for (int i = 0; i < 8; ++i) {
                hA[i] = fmaxf(fmaf(cA.x, wa[i], fmaf(cA.y, wb[i], bv[i])), 0.f);
                hB[i] = fmaxf(fmaf(cB.x, wa[i], fmaf(cB.y, wb[i], bv[i])), 0.f);
            }
            #pragma unroll
            for (int m = 0; m < 4; ++m) {
                B0.p[m] = __builtin_amdgcn_cvt_pkrtz(hA[2*m], hA[2*m+1]);
                B1.p[m] = __builtin_amdgcn_cvt_pkrtz(hB[2*m], hB[2*m+1]);
            }
        } else {
            #pragma unroll
            for (int m = 0; m < 4; ++m) { B0.u[m] = 0u; B1.u[m] = 0u; }
            if (kb == 200) { B0.u[0] = 0x3C00u; B1.u[0] = 0x3C00u; }  // ones row (bias)
        }
        acc00 = __builtin_amdgcn_mfma_f32_32x32x16_f16(a0, B0.h, acc00, 0, 0, 0);
        acc01 = __builtin_amdgcn_mfma_f32_32x32x16_f16(a0, B1.h, acc01, 0, 0, 0);
        acc10 = __builtin_amdgcn_mfma_f32_32x32x16_f16(a1, B0.h, acc10, 0, 0, 0);
        acc11 = __builtin_amdgcn_mfma_f32_32x32x16_f16(a1, B1.h, acc11, 0, 0, 0);
    };

    for (int ks = 0; ks < 6; ++ks) { step(ks, 0); step(ks, 1); }
    step(6, 0);

    uint32_t pk0[2][8], pk1[2][8];
    #pragma unroll
    for (int m = 0; m < 8; ++m) {
        union { fp16x2 p; uint32_t u; } q;
        q.p = __builtin_amdgcn_cvt_pkrtz(fmaxf(acc00[2*m], 0.f), fmaxf(acc00[2*m+1], 0.f));
        pk0[0][m] = q.u;
        q.p = __builtin_amdgcn_cvt_pkrtz(fmaxf(acc01[2*m], 0.f), fmaxf(acc01[2*m+1], 0.f));
        pk0[1][m] = q.u;
        q.p = __builtin_amdgcn_cvt_pkrtz(fmaxf(acc10[2*m], 0.f), fmaxf(acc10[2*m+1], 0.f));
        pk1[0][m] = q.u;
        q.p = __builtin_amdgcn_cvt_pkrtz(fmaxf(acc11[2*m], 0.f), fmaxf(acc11[2*m+1], 0.f));
        pk1[1][m] = q.u;
    }
    if (hl == 0) { pk1[0][5] = 0x3C00u; pk1[1][5] = 0x3C00u; }

    f32x16 acch0, acch1;
    #pragma unroll
    for (int r = 0; r < 16; ++r) { acch0[r] = 0.f; acch1[r] = 0.f; }

    #pragma unroll
    for (int kt = 0; kt < 4; ++kt) {
        half8 ah = *(const half8*)(whp + kt * 512 + lane * 8);
        const int bb = 4 * (kt & 1);
        #pragma unroll
        for (int ct = 0; ct < 2; ++ct) {
            const uint32_t e0 = (kt < 2) ? pk0[ct][bb + 0] : pk1[ct][bb + 0];
            const uint32_t e1 = (kt < 2) ? pk0[ct][bb + 1] : pk1[ct][bb + 1];
            const uint32_t e2 = (kt < 2) ? pk0[ct][bb + 2] : pk1[ct][bb + 2];
            const uint32_t e3 = (kt < 2) ? pk0[ct][bb + 3] : pk1[ct][bb + 3];
            const uint32_t o0 = hl ? e2 : e0;
            const uint32_t o1 = hl ? e3 : e1;
            const uint32_t s0 = hl ? e0 : e2;
            const uint32_t s1 = hl ? e1 : e3;
            const uint32_t g0 = (uint32_t)__shfl_xor((int)s0, 32);
            const uint32_t g1 = (uint32_t)__shfl_xor((int)s1, 32);
            union { half8 h; uint32_t u[4]; } BF;
            BF.u[0] = hl ? g0 : o0;
            BF.u[1] = hl ? g1 : o1;
            BF.u[2] = hl ? o0 : g0;
            BF.u[3] = hl ? o1 : g1;
            if (ct == 0) acch0 = __builtin_amdgcn_mfma_f32_32x32x16_f16(ah, BF.h, acch0, 0, 0, 0);
            else         acch1 = __builtin_amdgcn_mfma_f32_32x32x16_f16(ah, BF.h, acch1, 0, 0, 0);
        }
    }

    float s[9];
    #pragma unroll
    for (int r = 0; r < 4; ++r) {
        const float own  = hl ? acch1[r] : acch0[r];
        const float send = hl ? acch0[r] : acch1[r];
        const float got  = __shfl_xor(send, 32);
        s[r]     = hl ? got : own;
        s[4 + r] = hl ? own : got;
    }
    {
        const float own  = hl ? acch1[4] : acch0[4];
        const float send = hl ? acch0[4] : acch1[4];
        const float got  = __shfl_xor(send, 32);
        s[8] = hl ? got : own;
    }

    const int p   = p0 + lane;
    const int b   = p >> 16;
    const int pix = p & 65535;
    const int ph  = pix >> 8;
    const int pw  = pix & 255;

    float pan = s[4];
    #pragma unroll
    for (int c = 0; c < 4; ++c)
        pan = fmaf(hrhs[((b * 4 + c) << 16) + pix], s[c], pan);
    out_pan[p] = pan;

    if ((ph & 3) == 1 && (pw & 3) == 1) {
        const float v0 = s[5], v2 = s[7], v3 = s[8];
        const int hh = ph >> 2, ww = pw >> 2;
        const int o = ((b * LSZ + hh) * LSZ + ww) * 3;
        inv_ws[o + 0] = v0 * v0 + v2 * v2;
        inv_ws[o + 1] = v2 * v3;
        inv_ws[o + 2] = v3 * v3;
    }
}

// ---------------------------------------------------------------------------
// msi2: block = (b,hh). Phase 1: the 4 c-waves cooperatively compute each
// ww's 225 Gaussian weights ONCE into LDS (c-wave owns p-range). Phase 2:
// each thread (c,ww) does unconditional aligned float4 gathers from the
// padded plane and dots against the shared LDS weights.
// ---------------------------------------------------------------------------
__global__ __launch_bounds__(256) void msi2_kernel(
    const float* __restrict__ pad, const float* __restrict__ inv_ws,
    float* __restrict__ out_msi)
{
    __shared__ float ew[225 * 64];   // 57600 B, [p*15+q][ww]
    __shared__ float wsp[256];       // per-(c,ww) partial weight sums

    const int tid = threadIdx.x;
    const int ww  = tid & 63;
    const int c   = tid >> 6;        // wave-uniform
    const int hh  = blockIdx.x & 63;
    const int b   = blockIdx.x >> 6;

    const int o = ((b * LSZ + hh) * LSZ + ww) * 3;
    const float I00 = inv_ws[o + 0];
    const float I01 = inv_ws[o + 1];
    const float I11 = inv_ws[o + 2];

    // ---- phase 1: weights for p in [4c, 4c+4) (c=3: 12..14) ----
    float ws = 0.0f;
    #pragma unroll
    for (int pp = 0; pp < 4; ++pp) {
        const int p = c * 4 + pp;
        if (p > 14) break;           // wave-uniform branch
        const float dp = (float)(p - 7);
        const float a0 = I00 * dp * dp;
        const float a1 = 2.0f * I01 * dp;
        #pragma unroll
        for (int q = 0; q < 15; ++q) {
            const float dq = (float)(q - 7);
            const float tt = fmaf(a1, dq, fmaf(I11 * dq, dq, a0));
            const float e = __expf(-0.5f * tt);
            ew[(p * 15 + q) * 64 + ww] = e;
            ws += e;
        }
    }
    wsp[tid] = ws;
    __syncthreads();

    // ---- phase 2: gather + dot ----
    const float wsum = wsp[ww] + wsp[64 + ww] + wsp[128 + ww] + wsp[192 + ww];
    const float* plane = pad + (size_t)((b * 4 + c) * PROWS) * PCOLS;

    float acc = 0.0f;
    #pragma unroll
    for (int p = 0; p < 15; ++p) {
        const float* rowp = plane + (4 * hh + p) * PCOLS + 4 * ww;
        const float4 x0 = *(const float4*)(rowp);
        const float4 x1 = *(const float4*)(rowp + 4);
        const float4 x2 = *(const float4*)(rowp + 8);
        const float4 x3 = *(const float4*)(rowp + 12);
        const float xs[16] = {x0.x,x0.y,x0.z,x0.w, x1.x,x1.y,x1.z,x1.w,
                              x2.x,x2.y,x2.z,x2.w, x3.x,x3.y,x3.z,x3.w};
        #pragma unroll
        for (int q = 0; q < 15; ++q)
            acc = fmaf(xs[q], ew[(p * 15 + q) * 64 + ww], acc);
    }
    out_msi[((b * 4 + c) * LSZ + hh) * LSZ + ww] = acc / wsum;
}

extern "C" void kernel_launch(void* const* d_in, const int* in_sizes, int n_in,
                              void* d_out, int out_size, void* d_ws, size_t ws_size,
                              hipStream_t stream) {
    const float* coords = (const float*)d_in[0];
    const float* hrhs   = (const float*)d_in[1];
    const float* w1     = (const float*)d_in[2];
    const float* b1     = (const float*)d_in[3];
    const float* w2     = (const float*)d_in[4];
    const float* b2     = (const float*)d_in[5];
    const float* w_spek = (const float*)d_in[6];
    const float* b_spek = (const float*)d_in[7];
    const float* w_spak = (const float*)d_in[8];
    const float* b_spak = (const float*)d_in[9];

    float* out     = (float*)d_out;
    float* out_msi = out;                        // 8*4*64*64   = 131072
    float* out_pan = out + 8 * 4 * 64 * 64;      // 8*1*256*256 = 524288

    float*     inv_ws = (float*)d_ws;                         // 393216 B
    _Float16*  w2p    = (_Float16*)((char*)d_ws + 393216);    // 28672 B
    _Float16*  whp    = (_Float16*)((char*)d_ws + 421888);    // 4096 B
    float*     padbuf = (float*)((char*)d_ws + 425984);       // 9295872 B

    pack_kernel<<<64, 256, 0, stream>>>(w2, b2, w_spek, b_spek, w_spak, b_spak,
                                        w2p, whp);

    const int n_pad = 32 * PROWS * PCOLS;        // 2323968, % 256 == 0
    pad_kernel<<<n_pad / 256, 256, 0, stream>>>(hrhs, padbuf);

    mlp3_kernel<<<2048, 256, 0, stream>>>(
        coords, hrhs, w1, b1, w2p, whp, out_pan, inv_ws);

    msi2_kernel<<<512, 256, 0, stream>>>(padbuf, inv_ws, out_msi);
}

// Round 6
// 45.754 us; speedup vs baseline: 3.2925x; 1.1665x over previous
//
#include <hip/hip_runtime.h>

#define HRR 256
#define LSZ 64
#define KK  15
#define PROWS 267
#define PCOLS 272

typedef _Float16 half8  __attribute__((ext_vector_type(8)));
typedef __fp16   fp16x2 __attribute__((ext_vector_type(2)));
typedef __fp16   h2     __attribute__((ext_vector_type(2)));
typedef float    f32x16 __attribute__((ext_vector_type(16)));

#define PACK_THREADS 17152   // 67 blocks
#define PAD_N (32 * PROWS * PCOLS)

// ---------------------------------------------------------------------------
// Prep kernel: fuses weight packing (blocks 0..66) and hrhs zero-padding.
//  w2p: W2^T A-frags [rt(2)][f(14)][lane(64)][i(8)], k==200 -> b2 row.
//  whp: head A-frags [f(4)][lane(64)][i(8)], k==50 -> head-bias row.
//  w1p: layer-1 f16 pairs [f(13)][hl(2)][pr(12)][e(2)]:
//       pr 0-3 = wa pairs, 4-7 = wb pairs, 8-11 = bv pairs;
//       k = f*16+hl*8+(pr&3)*2+e; k==200 bias row encodes 1.0 in bv.
//  pad: [32][PROWS][PCOLS] zero-padded hrhs.
// ---------------------------------------------------------------------------
__global__ __launch_bounds__(256) void prep_kernel(
    const float* __restrict__ w1,     const float* __restrict__ b1,
    const float* __restrict__ w2,     const float* __restrict__ b2,
    const float* __restrict__ w_spek, const float* __restrict__ b_spek,
    const float* __restrict__ w_spak, const float* __restrict__ b_spak,
    const float* __restrict__ hrhs,
    _Float16* __restrict__ w2p, _Float16* __restrict__ whp,
    _Float16* __restrict__ w1p, float* __restrict__ pad)
{
    int gid = blockIdx.x * 256 + threadIdx.x;
    if (gid < PACK_THREADS) {
        int flat = gid;
        if (flat < 14336) {
            int rt = flat / 7168;
            int rem = flat % 7168;
            int f  = rem / 512;
            int r2 = rem % 512;
            int ln = r2 / 8;
            int i  = r2 % 8;
            int j = rt * 32 + (ln & 31);
            int k = f * 16 + (ln >> 5) * 8 + i;
            float v = 0.0f;
            if (j < 50) {
                if (k < 200)       v = w2[k * 50 + j];
                else if (k == 200) v = b2[j];
            }
            w2p[flat] = (_Float16)v;
        } else if (flat < 14336 + 2048) {
            int r  = flat - 14336;
            int f  = r / 512;
            int r2 = r % 512;
            int ln = r2 / 8;
            int i  = r2 % 8;
            int t = ln & 31;
            int k = f * 16 + (ln >> 5) * 8 + i;
            float v = 0.0f;
            if (t < 9) {
                if (k < 50)       v = (t < 5) ? w_spek[k * 5 + t] : w_spak[k * 4 + (t - 5)];
                else if (k == 50) v = (t < 5) ? b_spek[t] : b_spak[t - 5];
            }
            whp[r] = (_Float16)v;
        } else if (flat < 14336 + 2048 + 624) {
            int r = flat - (14336 + 2048);
            int e  = r & 1;
            int pr = (r >> 1) % 12;
            int hl = ((r >> 1) / 12) & 1;
            int f  = (r >> 1) / 24;
            int k  = f * 16 + hl * 8 + (pr & 3) * 2 + e;
            int sel = pr >> 2;                  // 0 wa, 1 wb, 2 bv
            float v = 0.0f;
            if (k < 200)       v = (sel == 0) ? w1[k] : (sel == 1) ? w1[200 + k] : b1[k];
            else if (k == 200 && sel == 2) v = 1.0f;   // bias ones-row
            w1p[r] = (_Float16)v;
        }
    } else {
        int i = gid - PACK_THREADS;
        if (i < PAD_N) {
            int pc   = i % PCOLS;
            int rest = i / PCOLS;
            int pr   = rest % PROWS;
            int bc   = rest / PROWS;
            int r    = pr - 6;
            int col  = pc - 6;
            float v = ((unsigned)r < 256u && (unsigned)col < 256u)
                          ? hrhs[(bc << 16) + (r << 8) + col] : 0.0f;
            pad[i] = v;
        }
    }
}

// ---------------------------------------------------------------------------
// Main MLP kernel: layer-1 via packed v_pk_fma_f16 directly into MFMA
// B-fragments; layer-2 + heads via MFMA; barrier-free after W2 staging.
// ---------------------------------------------------------------------------
__global__ __launch_bounds__(256) void mlp4_kernel(
    const float* __restrict__ coords, const float* __restrict__ hrhs,
    const _Float16* __restrict__ w1p,
    const _Float16* __restrict__ w2p, const _Float16* __restrict__ whp,
    float* __restrict__ out_pan,      float* __restrict__ inv_ws)
{
    __shared__ __align__(16) _Float16 W2s[14336];   // 28672 B

    const int tid  = threadIdx.x;
    const int lane = tid & 63;
    const int wv   = tid >> 6;
    const int hl   = lane >> 5;
    const int cl   = lane & 31;

    {
        const uint4* src = (const uint4*)w2p;
        uint4* dst = (uint4*)W2s;
        #pragma unroll
        for (int it = 0; it < 7; ++it)
            dst[it * 256 + tid] = src[it * 256 + tid];
    }
    __syncthreads();

    const int p0 = blockIdx.x * 256 + wv * 64;

    const float2 cA = ((const float2*)coords)[p0 + cl];        // ct = 0
    const float2 cB = ((const float2*)coords)[p0 + 32 + cl];   // ct = 1

    const __fp16 ax = (__fp16)cA.x, ay = (__fp16)cA.y;
    const __fp16 bx = (__fp16)cB.x, by = (__fp16)cB.y;
    const h2 cax2 = {ax, ax}, cay2 = {ay, ay};
    const h2 cbx2 = {bx, bx}, cby2 = {by, by};
    const h2 hz   = {(__fp16)0.f, (__fp16)0.f};

    f32x16 acc00, acc01, acc10, acc11;
    #pragma unroll
    for (int r = 0; r < 16; ++r) { acc00[r] = 0.f; acc01[r] = 0.f; acc10[r] = 0.f; acc11[r] = 0.f; }

    const h2* w1h = (const h2*)w1p;

    for (int f = 0; f < 13; ++f) {
        half8 a0 = *(const half8*)(W2s + f * 512 + lane * 8);
        half8 a1 = *(const half8*)(W2s + (14 + f) * 512 + lane * 8);

        union { uint4 u[3]; h2 p[12]; } W;
        const uint4* wp = (const uint4*)(w1h + (size_t)(f * 2 + hl) * 12);
        W.u[0] = wp[0]; W.u[1] = wp[1]; W.u[2] = wp[2];

        union { half8 h; h2 p[4]; } B0, B1;
        #pragma unroll
        for (int m = 0; m < 4; ++m) {
            h2 t0 = __builtin_elementwise_fma(W.p[4 + m], cay2, W.p[8 + m]);
            h2 r0 = __builtin_elementwise_fma(W.p[m],     cax2, t0);
            B0.p[m] = __builtin_elementwise_max(r0, hz);
            h2 t1 = __builtin_elementwise_fma(W.p[4 + m], cby2, W.p[8 + m]);
            h2 r1 = __builtin_elementwise_fma(W.p[m],     cbx2, t1);
            B1.p[m] = __builtin_elementwise_max(r1, hz);
        }

        acc00 = __builtin_amdgcn_mfma_f32_32x32x16_f16(a0, B0.h, acc00, 0, 0, 0);
        acc01 = __builtin_amdgcn_mfma_f32_32x32x16_f16(a0, B1.h, acc01, 0, 0, 0);
        acc10 = __builtin_amdgcn_mfma_f32_32x32x16_f16(a1, B0.h, acc10, 0, 0, 0);
        acc11 = __builtin_amdgcn_mfma_f32_32x32x16_f16(a1, B1.h, acc11, 0, 0, 0);
    }

    uint32_t pk0[2][8], pk1[2][8];
    #pragma unroll
    for (int m = 0; m < 8; ++m) {
        union { fp16x2 p; uint32_t u; } q;
        q.p = __builtin_amdgcn_cvt_pkrtz(fmaxf(acc00[2*m], 0.f), fmaxf(acc00[2*m+1], 0.f));
        pk0[0][m] = q.u;
        q.p = __builtin_amdgcn_cvt_pkrtz(fmaxf(acc01[2*m], 0.f), fmaxf(acc01[2*m+1], 0.f));
        pk0[1][m] = q.u;
        q.p = __builtin_amdgcn_cvt_pkrtz(fmaxf(acc10[2*m], 0.f), fmaxf(acc10[2*m+1], 0.f));
        pk1[0][m] = q.u;
        q.p = __builtin_amdgcn_cvt_pkrtz(fmaxf(acc11[2*m], 0.f), fmaxf(acc11[2*m+1], 0.f));
        pk1[1][m] = q.u;
    }
    if (hl == 0) { pk1[0][5] = 0x3C00u; pk1[1][5] = 0x3C00u; }  // F-row 50 = 1

    f32x16 acch0, acch1;
    #pragma unroll
    for (int r = 0; r < 16; ++r) { acch0[r] = 0.f; acch1[r] = 0.f; }

    #pragma unroll
    for (int kt = 0; kt < 4; ++kt) {
        half8 ah = *(const half8*)(whp + kt * 512 + lane * 8);
        const int bb = 4 * (kt & 1);
        #pragma unroll
        for (int ct = 0; ct < 2; ++ct) {
            const uint32_t e0 = (kt < 2) ? pk0[ct][bb + 0] : pk1[ct][bb + 0];
            const uint32_t e1 = (kt < 2) ? pk0[ct][bb + 1] : pk1[ct][bb + 1];
            const uint32_t e2 = (kt < 2) ? pk0[ct][bb + 2] : pk1[ct][bb + 2];
            const uint32_t e3 = (kt < 2) ? pk0[ct][bb + 3] : pk1[ct][bb + 3];
            const uint32_t o0 = hl ? e2 : e0;
            const uint32_t o1 = hl ? e3 : e1;
            const uint32_t s0 = hl ? e0 : e2;
            const uint32_t s1 = hl ? e1 : e3;
            const uint32_t g0 = (uint32_t)__shfl_xor((int)s0, 32);
            const uint32_t g1 = (uint32_t)__shfl_xor((int)s1, 32);
            union { half8 h; uint32_t u[4]; } BF;
            BF.u[0] = hl ? g0 : o0;
            BF.u[1] = hl ? g1 : o1;
            BF.u[2] = hl ? o0 : g0;
            BF.u[3] = hl ? o1 : g1;
            if (ct == 0) acch0 = __builtin_amdgcn_mfma_f32_32x32x16_f16(ah, BF.h, acch0, 0, 0, 0);
            else         acch1 = __builtin_amdgcn_mfma_f32_32x32x16_f16(ah, BF.h, acch1, 0, 0, 0);
        }
    }

    float s[9];
    #pragma unroll
    for (int r = 0; r < 4; ++r) {
        const float own  = hl ? acch1[r] : acch0[r];
        const float send = hl ? acch0[r] : acch1[r];
        const float got  = __shfl_xor(send, 32);
        s[r]     = hl ? got : own;
        s[4 + r] = hl ? own : got;
    }
    {
        const float own  = hl ? acch1[4] : acch0[4];
        const float send = hl ? acch0[4] : acch1[4];
        const float got  = __shfl_xor(send, 32);
        s[8] = hl ? got : own;
    }

    const int p   = p0 + lane;
    const int b   = p >> 16;
    const int pix = p & 65535;
    const int ph  = pix >> 8;
    const int pw  = pix & 255;

    float pan = s[4];
    #pragma unroll
    for (int c = 0; c < 4; ++c)
        pan = fmaf(hrhs[((b * 4 + c) << 16) + pix], s[c], pan);
    out_pan[p] = pan;

    if ((ph & 3) == 1 && (pw & 3) == 1) {
        const float v0 = s[5], v2 = s[7], v3 = s[8];
        const int hh = ph >> 2, ww = pw >> 2;
        const int o = ((b * LSZ + hh) * LSZ + ww) * 3;
        inv_ws[o + 0] = v0 * v0 + v2 * v2;
        inv_ws[o + 1] = v2 * v3;
        inv_ws[o + 2] = v3 * v3;
    }
}

// ---------------------------------------------------------------------------
// msi2 (unchanged from round 5): shared Gaussian weights in LDS + float4
// gathers from padded planes.
// ---------------------------------------------------------------------------
__global__ __launch_bounds__(256) void msi2_kernel(
    const float* __restrict__ pad, const float* __restrict__ inv_ws,
    float* __restrict__ out_msi)
{
    __shared__ float ew[225 * 64];   // 57600 B, [p*15+q][ww]
    __shared__ float wsp[256];

    const int tid = threadIdx.x;
    const int ww  = tid & 63;
    const int c   = tid >> 6;
    const int hh  = blockIdx.x & 63;
    const int b   = blockIdx.x >> 6;

    const int o = ((b * LSZ + hh) * LSZ + ww) * 3;
    const float I00 = inv_ws[o + 0];
    const float I01 = inv_ws[o + 1];
    const float I11 = inv_ws[o + 2];

    float ws = 0.0f;
    #pragma unroll
    for (int pp = 0; pp < 4; ++pp) {
        const int p = c * 4 + pp;
        if (p > 14) break;
        const float dp = (float)(p - 7);
        const float a0 = I00 * dp * dp;
        const float a1 = 2.0f * I01 * dp;
        #pragma unroll
        for (int q = 0; q < 15; ++q) {
            const float dq = (float)(q - 7);
            const float tt = fmaf(a1, dq, fmaf(I11 * dq, dq, a0));
            const float e = __expf(-0.5f * tt);
            ew[(p * 15 + q) * 64 + ww] = e;
            ws += e;
        }
    }
    wsp[tid] = ws;
    __syncthreads();

    const float wsum = wsp[ww] + wsp[64 + ww] + wsp[128 + ww] + wsp[192 + ww];
    const float* plane = pad + (size_t)((b * 4 + c) * PROWS) * PCOLS;

    float acc = 0.0f;
    #pragma unroll
    for (int p = 0; p < 15; ++p) {
        const float* rowp = plane + (4 * hh + p) * PCOLS + 4 * ww;
        const float4 x0 = *(const float4*)(rowp);
        const float4 x1 = *(const float4*)(rowp + 4);
        const float4 x2 = *(const float4*)(rowp + 8);
        const float4 x3 = *(const float4*)(rowp + 12);
        const float xs[16] = {x0.x,x0.y,x0.z,x0.w, x1.x,x1.y,x1.z,x1.w,
                              x2.x,x2.y,x2.z,x2.w, x3.x,x3.y,x3.z,x3.w};
        #pragma unroll
        for (int q = 0; q < 15; ++q)
            acc = fmaf(xs[q], ew[(p * 15 + q) * 64 + ww], acc);
    }
    out_msi[((b * 4 + c) * LSZ + hh) * LSZ + ww] = acc / wsum;
}

extern "C" void kernel_launch(void* const* d_in, const int* in_sizes, int n_in,
                              void* d_out, int out_size, void* d_ws, size_t ws_size,
                              hipStream_t stream) {
    const float* coords = (const float*)d_in[0];
    const float* hrhs   = (const float*)d_in[1];
    const float* w1     = (const float*)d_in[2];
    const float* b1     = (const float*)d_in[3];
    const float* w2     = (const float*)d_in[4];
    const float* b2     = (const float*)d_in[5];
    const float* w_spek = (const float*)d_in[6];
    const float* b_spek = (const float*)d_in[7];
    const float* w_spak = (const float*)d_in[8];
    const float* b_spak = (const float*)d_in[9];

    float* out     = (float*)d_out;
    float* out_msi = out;                        // 8*4*64*64   = 131072
    float* out_pan = out + 8 * 4 * 64 * 64;      // 8*1*256*256 = 524288

    float*     inv_ws = (float*)d_ws;                         // 393216 B
    _Float16*  w2p    = (_Float16*)((char*)d_ws + 393216);    // 28672 B
    _Float16*  whp    = (_Float16*)((char*)d_ws + 421888);    // 4096 B
    _Float16*  w1p    = (_Float16*)((char*)d_ws + 425984);    // 4096 B (1248 used)
    float*     padbuf = (float*)((char*)d_ws + 430080);       // 9295872 B

    const int n_prep = PACK_THREADS / 256 + PAD_N / 256;      // 67 + 9078
    prep_kernel<<<n_prep, 256, 0, stream>>>(
        w1, b1, w2, b2, w_spek, b_spek, w_spak, b_spak, hrhs,
        w2p, whp, w1p, padbuf);

    mlp4_kernel<<<2048, 256, 0, stream>>>(
        coords, hrhs, w1p, w2p, whp, out_pan, inv_ws);

    msi2_kernel<<<512, 256, 0, stream>>>(padbuf, inv_ws, out_msi);
}

// Round 8
// 39.815 us; speedup vs baseline: 3.7837x; 1.1492x over previous
//
#include <hip/hip_runtime.h>

#define HRR 256
#define LSZ 64
#define KK  15
#define PROWS 267
#define PCOLS 272

typedef _Float16 half8  __attribute__((ext_vector_type(8)));
typedef __fp16   fp16x2 __attribute__((ext_vector_type(2)));
typedef __fp16   h2     __attribute__((ext_vector_type(2)));
typedef float    f32x16 __attribute__((ext_vector_type(16)));

#define PACK_THREADS 17152   // 67 blocks
#define PAD_N (32 * PROWS * PCOLS)

// ---------------------------------------------------------------------------
// Prep kernel: weight packing (blocks 0..66) + hrhs zero-padding (rest).
// Layouts unchanged from round 6.
// ---------------------------------------------------------------------------
__global__ __launch_bounds__(256) void prep_kernel(
    const float* __restrict__ w1,     const float* __restrict__ b1,
    const float* __restrict__ w2,     const float* __restrict__ b2,
    const float* __restrict__ w_spek, const float* __restrict__ b_spek,
    const float* __restrict__ w_spak, const float* __restrict__ b_spak,
    const float* __restrict__ hrhs,
    _Float16* __restrict__ w2p, _Float16* __restrict__ whp,
    _Float16* __restrict__ w1p, float* __restrict__ pad)
{
    int gid = blockIdx.x * 256 + threadIdx.x;
    if (gid < PACK_THREADS) {
        int flat = gid;
        if (flat < 14336) {
            int rt = flat / 7168;
            int rem = flat % 7168;
            int f  = rem / 512;
            int r2 = rem % 512;
            int ln = r2 / 8;
            int i  = r2 % 8;
            int j = rt * 32 + (ln & 31);
            int k = f * 16 + (ln >> 5) * 8 + i;
            float v = 0.0f;
            if (j < 50) {
                if (k < 200)       v = w2[k * 50 + j];
                else if (k == 200) v = b2[j];
            }
            w2p[flat] = (_Float16)v;
        } else if (flat < 14336 + 2048) {
            int r  = flat - 14336;
            int f  = r / 512;
            int r2 = r % 512;
            int ln = r2 / 8;
            int i  = r2 % 8;
            int t = ln & 31;
            int k = f * 16 + (ln >> 5) * 8 + i;
            float v = 0.0f;
            if (t < 9) {
                if (k < 50)       v = (t < 5) ? w_spek[k * 5 + t] : w_spak[k * 4 + (t - 5)];
                else if (k == 50) v = (t < 5) ? b_spek[t] : b_spak[t - 5];
            }
            whp[r] = (_Float16)v;
        } else if (flat < 14336 + 2048 + 624) {
            int r = flat - (14336 + 2048);
            int e  = r & 1;
            int pr = (r >> 1) % 12;
            int hl = ((r >> 1) / 12) & 1;
            int f  = (r >> 1) / 24;
            int k  = f * 16 + hl * 8 + (pr & 3) * 2 + e;
            int sel = pr >> 2;                  // 0 wa, 1 wb, 2 bv
            float v = 0.0f;
            if (k < 200)       v = (sel == 0) ? w1[k] : (sel == 1) ? w1[200 + k] : b1[k];
            else if (k == 200 && sel == 2) v = 1.0f;   // bias ones-row
            w1p[r] = (_Float16)v;
        }
    } else {
        int i = gid - PACK_THREADS;
        if (i < PAD_N) {
            int pc   = i % PCOLS;
            int rest = i / PCOLS;
            int pr   = rest % PROWS;
            int bc   = rest / PROWS;
            int r    = pr - 6;
            int col  = pc - 6;
            float v = ((unsigned)r < 256u && (unsigned)col < 256u)
                          ? hrhs[(bc << 16) + (r << 8) + col] : 0.0f;
            pad[i] = v;
        }
    }
}

// ---------------------------------------------------------------------------
// Main MLP kernel. Round-8: round-7 structure with the W1s staging bug fixed
// (312 dwords need TWO strided writes from 256 threads; `tid<312` left
// dwords 256..311 = f>=11 weights uninitialized -> NaN cascade).
//  * __launch_bounds__(256, 4): cap VGPR at 128 -> >=4 waves/SIMD.
//  * W1 packed weights in LDS: K-loop is pure LDS + VALU + MFMA.
// ---------------------------------------------------------------------------
__global__ __launch_bounds__(256, 4) void mlp5_kernel(
    const float* __restrict__ coords, const float* __restrict__ hrhs,
    const _Float16* __restrict__ w1p,
    const _Float16* __restrict__ w2p, const _Float16* __restrict__ whp,
    float* __restrict__ out_pan,      float* __restrict__ inv_ws)
{
    __shared__ __align__(16) _Float16 W2s[14336];   // 28672 B
    __shared__ __align__(16) _Float16 W1s[624];     // 1248 B

    const int tid  = threadIdx.x;
    const int lane = tid & 63;
    const int wv   = tid >> 6;
    const int hl   = lane >> 5;
    const int cl   = lane & 31;

    {
        const uint4* src = (const uint4*)w2p;
        uint4* dst = (uint4*)W2s;
        #pragma unroll
        for (int it = 0; it < 7; ++it)
            dst[it * 256 + tid] = src[it * 256 + tid];
        // stage 312 dwords of W1 with two strided writes (FIX vs round 7)
        ((unsigned*)W1s)[tid] = ((const unsigned*)w1p)[tid];
        if (tid < 56)
            ((unsigned*)W1s)[256 + tid] = ((const unsigned*)w1p)[256 + tid];
    }
    __syncthreads();

    const int p0 = blockIdx.x * 256 + wv * 64;

    const float2 cA = ((const float2*)coords)[p0 + cl];        // ct = 0
    const float2 cB = ((const float2*)coords)[p0 + 32 + cl];   // ct = 1

    const __fp16 ax = (__fp16)cA.x, ay = (__fp16)cA.y;
    const __fp16 bx = (__fp16)cB.x, by = (__fp16)cB.y;
    const h2 cax2 = {ax, ax}, cay2 = {ay, ay};
    const h2 cbx2 = {bx, bx}, cby2 = {by, by};
    const h2 hz   = {(__fp16)0.f, (__fp16)0.f};

    f32x16 acc00, acc01, acc10, acc11;
    #pragma unroll
    for (int r = 0; r < 16; ++r) { acc00[r] = 0.f; acc01[r] = 0.f; acc10[r] = 0.f; acc11[r] = 0.f; }

    // per-lane W1 base for this half-wave's k-octet (24 halves per (f,hl))
    const _Float16* w1base = W1s + hl * 24;

    for (int f = 0; f < 13; ++f) {
        half8 a0 = *(const half8*)(W2s + f * 512 + lane * 8);
        half8 a1 = *(const half8*)(W2s + (14 + f) * 512 + lane * 8);

        union { uint4 u[3]; h2 p[12]; } W;
        const uint4* wp = (const uint4*)(w1base + f * 48);
        W.u[0] = wp[0]; W.u[1] = wp[1]; W.u[2] = wp[2];

        union { half8 h; h2 p[4]; } B0, B1;
        #pragma unroll
        for (int m = 0; m < 4; ++m) {
            h2 t0 = __builtin_elementwise_fma(W.p[4 + m], cay2, W.p[8 + m]);
            h2 r0 = __builtin_elementwise_fma(W.p[m],     cax2, t0);
            B0.p[m] = __builtin_elementwise_max(r0, hz);
            h2 t1 = __builtin_elementwise_fma(W.p[4 + m], cby2, W.p[8 + m]);
            h2 r1 = __builtin_elementwise_fma(W.p[m],     cbx2, t1);
            B1.p[m] = __builtin_elementwise_max(r1, hz);
        }

        acc00 = __builtin_amdgcn_mfma_f32_32x32x16_f16(a0, B0.h, acc00, 0, 0, 0);
        acc01 = __builtin_amdgcn_mfma_f32_32x32x16_f16(a0, B1.h, acc01, 0, 0, 0);
        acc10 = __builtin_amdgcn_mfma_f32_32x32x16_f16(a1, B0.h, acc10, 0, 0, 0);
        acc11 = __builtin_amdgcn_mfma_f32_32x32x16_f16(a1, B1.h, acc11, 0, 0, 0);
    }

    uint32_t pk0[2][8], pk1[2][8];
    #pragma unroll
    for (int m = 0; m < 8; ++m) {
        union { fp16x2 p; uint32_t u; } q;
        q.p = __builtin_amdgcn_cvt_pkrtz(fmaxf(acc00[2*m], 0.f), fmaxf(acc00[2*m+1], 0.f));
        pk0[0][m] = q.u;
        q.p = __builtin_amdgcn_cvt_pkrtz(fmaxf(acc01[2*m], 0.f), fmaxf(acc01[2*m+1], 0.f));
        pk0[1][m] = q.u;
        q.p = __builtin_amdgcn_cvt_pkrtz(fmaxf(acc10[2*m], 0.f), fmaxf(acc10[2*m+1], 0.f));
        pk1[0][m] = q.u;
        q.p = __builtin_amdgcn_cvt_pkrtz(fmaxf(acc11[2*m], 0.f), fmaxf(acc11[2*m+1], 0.f));
        pk1[1][m] = q.u;
    }
    if (hl == 0) { pk1[0][5] = 0x3C00u; pk1[1][5] = 0x3C00u; }  // F-row 50 = 1

    f32x16 acch0, acch1;
    #pragma unroll
    for (int r = 0; r < 16; ++r) { acch0[r] = 0.f; acch1[r] = 0.f; }

    #pragma unroll
    for (int kt = 0; kt < 4; ++kt) {
        half8 ah = *(const half8*)(whp + kt * 512 + lane * 8);
        const int bb = 4 * (kt & 1);
        #pragma unroll
        for (int ct = 0; ct < 2; ++ct) {
            const uint32_t e0 = (kt < 2) ? pk0[ct][bb + 0] : pk1[ct][bb + 0];
            const uint32_t e1 = (kt < 2) ? pk0[ct][bb + 1] : pk1[ct][bb + 1];
            const uint32_t e2 = (kt < 2) ? pk0[ct][bb + 2] : pk1[ct][bb + 2];
            const uint32_t e3 = (kt < 2) ? pk0[ct][bb + 3] : pk1[ct][bb + 3];
            const uint32_t o0 = hl ? e2 : e0;
            const uint32_t o1 = hl ? e3 : e1;
            const uint32_t s0 = hl ? e0 : e2;
            const uint32_t s1 = hl ? e1 : e3;
            const uint32_t g0 = (uint32_t)__shfl_xor((int)s0, 32);
            const uint32_t g1 = (uint32_t)__shfl_xor((int)s1, 32);
            union { half8 h; uint32_t u[4]; } BF;
            BF.u[0] = hl ? g0 : o0;
            BF.u[1] = hl ? g1 : o1;
            BF.u[2] = hl ? o0 : g0;
            BF.u[3] = hl ? o1 : g1;
            if (ct == 0) acch0 = __builtin_amdgcn_mfma_f32_32x32x16_f16(ah, BF.h, acch0, 0, 0, 0);
            else         acch1 = __builtin_amdgcn_mfma_f32_32x32x16_f16(ah, BF.h, acch1, 0, 0, 0);
        }
    }

    float s[9];
    #pragma unroll
    for (int r = 0; r < 4; ++r) {
        const float own  = hl ? acch1[r] : acch0[r];
        const float send = hl ? acch0[r] : acch1[r];
        const float got  = __shfl_xor(send, 32);
        s[r]     = hl ? got : own;
        s[4 + r] = hl ? own : got;
    }
    {
        const float own  = hl ? acch1[4] : acch0[4];
        const float send = hl ? acch0[4] : acch1[4];
        const float got  = __shfl_xor(send, 32);
        s[8] = hl ? got : own;
    }

    const int p   = p0 + lane;
    const int b   = p >> 16;
    const int pix = p & 65535;
    const int ph  = pix >> 8;
    const int pw  = pix & 255;

    float pan = s[4];
    #pragma unroll
    for (int c = 0; c < 4; ++c)
        pan = fmaf(hrhs[((b * 4 + c) << 16) + pix], s[c], pan);
    out_pan[p] = pan;

    if ((ph & 3) == 1 && (pw & 3) == 1) {
        const float v0 = s[5], v2 = s[7], v3 = s[8];
        const int hh = ph >> 2, ww = pw >> 2;
        const int o = ((b * LSZ + hh) * LSZ + ww) * 3;
        inv_ws[o + 0] = v0 * v0 + v2 * v2;
        inv_ws[o + 1] = v2 * v3;
        inv_ws[o + 2] = v3 * v3;
    }
}

// ---------------------------------------------------------------------------
// msi2 (unchanged): shared Gaussian weights in LDS + float4 gathers from
// padded planes.
// ---------------------------------------------------------------------------
__global__ __launch_bounds__(256) void msi2_kernel(
    const float* __restrict__ pad, const float* __restrict__ inv_ws,
    float* __restrict__ out_msi)
{
    __shared__ float ew[225 * 64];   // 57600 B, [p*15+q][ww]
    __shared__ float wsp[256];

    const int tid = threadIdx.x;
    const int ww  = tid & 63;
    const int c   = tid >> 6;
    const int hh  = blockIdx.x & 63;
    const int b   = blockIdx.x >> 6;

    const int o = ((b * LSZ + hh) * LSZ + ww) * 3;
    const float I00 = inv_ws[o + 0];
    const float I01 = inv_ws[o + 1];
    const float I11 = inv_ws[o + 2];

    float ws = 0.0f;
    #pragma unroll
    for (int pp = 0; pp < 4; ++pp) {
        const int p = c * 4 + pp;
        if (p > 14) break;
        const float dp = (float)(p - 7);
        const float a0 = I00 * dp * dp;
        const float a1 = 2.0f * I01 * dp;
        #pragma unroll
        for (int q = 0; q < 15; ++q) {
            const float dq = (float)(q - 7);
            const float tt = fmaf(a1, dq, fmaf(I11 * dq, dq, a0));
            const float e = __expf(-0.5f * tt);
            ew[(p * 15 + q) * 64 + ww] = e;
            ws += e;
        }
    }
    wsp[tid] = ws;
    __syncthreads();

    const float wsum = wsp[ww] + wsp[64 + ww] + wsp[128 + ww] + wsp[192 + ww];
    const float* plane = pad + (size_t)((b * 4 + c) * PROWS) * PCOLS;

    float acc = 0.0f;
    #pragma unroll
    for (int p = 0; p < 15; ++p) {
        const float* rowp = plane + (4 * hh + p) * PCOLS + 4 * ww;
        const float4 x0 = *(const float4*)(rowp);
        const float4 x1 = *(const float4*)(rowp + 4);
        const float4 x2 = *(const float4*)(rowp + 8);
        const float4 x3 = *(const float4*)(rowp + 12);
        const float xs[16] = {x0.x,x0.y,x0.z,x0.w, x1.x,x1.y,x1.z,x1.w,
                              x2.x,x2.y,x2.z,x2.w, x3.x,x3.y,x3.z,x3.w};
        #pragma unroll
        for (int q = 0; q < 15; ++q)
            acc = fmaf(xs[q], ew[(p * 15 + q) * 64 + ww], acc);
    }
    out_msi[((b * 4 + c) * LSZ + hh) * LSZ + ww] = acc / wsum;
}

extern "C" void kernel_launch(void* const* d_in, const int* in_sizes, int n_in,
                              void* d_out, int out_size, void* d_ws, size_t ws_size,
                              hipStream_t stream) {
    const float* coords = (const float*)d_in[0];
    const float* hrhs   = (const float*)d_in[1];
    const float* w1     = (const float*)d_in[2];
    const float* b1     = (const float*)d_in[3];
    const float* w2     = (const float*)d_in[4];
    const float* b2     = (const float*)d_in[5];
    const float* w_spek = (const float*)d_in[6];
    const float* b_spek = (const float*)d_in[7];
    const float* w_spak = (const float*)d_in[8];
    const float* b_spak = (const float*)d_in[9];

    float* out     = (float*)d_out;
    float* out_msi = out;                        // 8*4*64*64   = 131072
    float* out_pan = out + 8 * 4 * 64 * 64;      // 8*1*256*256 = 524288

    float*     inv_ws = (float*)d_ws;                         // 393216 B
    _Float16*  w2p    = (_Float16*)((char*)d_ws + 393216);    // 28672 B
    _Float16*  whp    = (_Float16*)((char*)d_ws + 421888);    // 4096 B
    _Float16*  w1p    = (_Float16*)((char*)d_ws + 425984);    // 4096 B (1248 used)
    float*     padbuf = (float*)((char*)d_ws + 430080);       // 9295872 B

    const int n_prep = PACK_THREADS / 256 + PAD_N / 256;      // 67 + 9078
    prep_kernel<<<n_prep, 256, 0, stream>>>(
        w1, b1, w2, b2, w_spek, b_spek, w_spak, b_spak, hrhs,
        w2p, whp, w1p, padbuf);

    mlp5_kernel<<<2048, 256, 0, stream>>>(
        coords, hrhs, w1p, w2p, whp, out_pan, inv_ws);

    msi2_kernel<<<512, 256, 0, stream>>>(padbuf, inv_ws, out_msi);
}